// Round 6
// baseline (283.066 us; speedup 1.0000x reference)
//
#include <hip/hip_runtime.h>
#include <hip/hip_bf16.h>
#include <cmath>

#define T_DIM 2048
#define B_DIM 16
#define D_DIM 256
#define BD (B_DIM * D_DIM)
#define BM 128
#define BN 64
#define NEG_INF_F (-1e30f)

typedef __attribute__((ext_vector_type(8))) short bf16x8;
typedef __attribute__((ext_vector_type(4))) float f32x4;

union BF8 { ushort u[8]; bf16x8 v; };

static __device__ __forceinline__ ushort f2bf_rn(float f) {
    union { __hip_bfloat16 h; ushort u; } x;
    x.h = __float2bfloat16(f);   // compiler fuses pairs into v_cvt_pk_bf16_f32
    return x.u;
}

static __device__ __forceinline__ bf16x8 pack8(float4 v0, float4 v1, float s) {
    BF8 t;
    t.u[0] = f2bf_rn(v0.x * s); t.u[1] = f2bf_rn(v0.y * s);
    t.u[2] = f2bf_rn(v0.z * s); t.u[3] = f2bf_rn(v0.w * s);
    t.u[4] = f2bf_rn(v1.x * s); t.u[5] = f2bf_rn(v1.y * s);
    t.u[6] = f2bf_rn(v1.z * s); t.u[7] = f2bf_rn(v1.w * s);
    return t.v;
}

// ---------------- Phase A: barrier-free, LDS-free, f32-direct ----------------
// Each wave independently computes a 32-row x chunk partial LSE. B-fragments
// are gathered straight from global f32 (L2/L3-served, ~4x redundant across
// the block's waves) and converted in-register. No __syncthreads anywhere.
__global__ __launch_bounds__(256) void partial_lse_direct_kernel(
    const float* __restrict__ q1, const float* __restrict__ k2,
    const float* __restrict__ q2, const float* __restrict__ k1,
    const int* __restrict__ len_q1, const int* __restrict__ len_k2,
    const int* __restrict__ len_q2, const int* __restrict__ len_k1,
    float2* __restrict__ partial, float* __restrict__ diag,
    int chunk, int NS)
{
    const int pair = blockIdx.z / NS;
    const int sc   = blockIdx.z % NS;
    const int b    = blockIdx.y;
    const int t0   = blockIdx.x * BM;

    const float* pred = (pair == 0) ? q1 : q2;
    const float* targ = (pair == 0) ? k2 : k1;
    const int lp = (pair == 0) ? len_q1[b] : len_q2[b];
    const int lt = (pair == 0) ? len_k2[b] : len_k1[b];
    const int m  = min(lp, lt);
    const int s_start = sc * chunk;
    if (t0 >= m || s_start >= m) return;   // block-uniform early exit
    const int s_hi = min(m, s_start + chunk);
    const int pb = pair * B_DIM + b;

    const int tid = threadIdx.x;
    const int w   = tid >> 6;     // wave id (waves fully independent)
    const int l   = tid & 63;
    const int c   = l & 15;       // MFMA row/col-within-16
    const int g   = l >> 4;       // k-group

    // ---- preload pred rows [t0+32w, +32) as bf16 A-fragments, x10 folded in
    bf16x8 afrag[2][8];
    #pragma unroll
    for (int i = 0; i < 2; ++i) {
        const float* base = &pred[(size_t)(t0 + 32 * w + 16 * i + c) * BD
                                  + (size_t)b * D_DIM + g * 8];
        #pragma unroll
        for (int kk = 0; kk < 8; ++kk) {
            const float4 a0 = *reinterpret_cast<const float4*>(base + kk * 32);
            const float4 a1 = *reinterpret_cast<const float4*>(base + kk * 32 + 4);
            afrag[i][kk] = pack8(a0, a1, 10.0f);
        }
    }

    float tmax[2][4], tsum[2][4], dg[2][4];
    #pragma unroll
    for (int i = 0; i < 2; ++i)
        #pragma unroll
        for (int rr = 0; rr < 4; ++rr) {
            tmax[i][rr] = NEG_INF_F; tsum[i][rr] = 0.0f; dg[i][rr] = NEG_INF_F;
        }

    for (int s0 = s_start; s0 < s_hi; s0 += BN) {
        const float* trow = &targ[(size_t)(s0 + c) * BD + (size_t)b * D_DIM + g * 8];

        f32x4 acc[2][4];
        #pragma unroll
        for (int i = 0; i < 2; ++i)
            #pragma unroll
            for (int j = 0; j < 4; ++j)
                acc[i][j] = (f32x4){0.f, 0.f, 0.f, 0.f};

        #pragma unroll
        for (int kk = 0; kk < 8; ++kk) {
            bf16x8 bfrag[4];
            #pragma unroll
            for (int j = 0; j < 4; ++j) {
                const float* p = trow + (size_t)j * 16 * BD;
                const float4 u0 = *reinterpret_cast<const float4*>(p + kk * 32);
                const float4 u1 = *reinterpret_cast<const float4*>(p + kk * 32 + 4);
                bfrag[j] = pack8(u0, u1, 1.0f);
            }
            #pragma unroll
            for (int i = 0; i < 2; ++i)
                #pragma unroll
                for (int j = 0; j < 4; ++j)
                    acc[i][j] = __builtin_amdgcn_mfma_f32_16x16x32_bf16(
                        afrag[i][kk], bfrag[j], acc[i][j], 0, 0, 0);
        }

        // ---- thread-local online LSE update
        #pragma unroll
        for (int i = 0; i < 2; ++i) {
            #pragma unroll
            for (int rr = 0; rr < 4; ++rr) {
                const int trow_i = t0 + 32 * w + 16 * i + 4 * g + rr;
                float lg[4];
                float cmax = NEG_INF_F;
                #pragma unroll
                for (int j = 0; j < 4; ++j) {
                    const int s = s0 + 16 * j + c;
                    float v = acc[i][j][rr];
                    v = (s < m) ? v : NEG_INF_F;
                    if (s == trow_i) dg[i][rr] = v;
                    lg[j] = v;
                    cmax = fmaxf(cmax, v);
                }
                const float nmax = fmaxf(tmax[i][rr], cmax);
                const float add = __expf(lg[0] - nmax) + __expf(lg[1] - nmax)
                                + __expf(lg[2] - nmax) + __expf(lg[3] - nmax);
                tsum[i][rr] = tsum[i][rr] * __expf(tmax[i][rr] - nmax) + add;
                tmax[i][rr] = nmax;
            }
        }
    }

    // ---- 16-lane LSE merge + writes (once per block)
    const bool own_diag = (t0 >= s_start) && (t0 + BM <= s_start + chunk);
    #pragma unroll
    for (int i = 0; i < 2; ++i) {
        #pragma unroll
        for (int rr = 0; rr < 4; ++rr) {
            float M = tmax[i][rr], S = tsum[i][rr];
            #pragma unroll
            for (int msk = 1; msk < 16; msk <<= 1) {
                const float Mo = __shfl_xor(M, msk, 64);
                const float So = __shfl_xor(S, msk, 64);
                const float nM = fmaxf(M, Mo);
                S = S * __expf(M - nM) + So * __expf(Mo - nM);
                M = nM;
            }
            float d = dg[i][rr];
            #pragma unroll
            for (int msk = 1; msk < 16; msk <<= 1)
                d = fmaxf(d, __shfl_xor(d, msk, 64));
            if (c == 0) {
                const int trow_i = t0 + 32 * w + 16 * i + 4 * g + rr;
                partial[((size_t)(pb << 11) + trow_i) * NS + sc] = make_float2(M, S);
                if (own_diag) diag[(pb << 11) + trow_i] = d;
            }
        }
    }
}

// ---------------- Phase B: merge chunk partials, per-sample loss ----------------
__global__ __launch_bounds__(256) void combine_kernel(
    const int* __restrict__ len_q1, const int* __restrict__ len_k2,
    const int* __restrict__ len_q2, const int* __restrict__ len_k1,
    const float2* __restrict__ partial, const float* __restrict__ diag,
    float* __restrict__ per_sample, int chunk, int NS)
{
    const int pb   = blockIdx.x;
    const int pair = pb >> 4;
    const int b    = pb & 15;
    const int lp = (pair == 0) ? len_q1[b] : len_q2[b];
    const int lt = (pair == 0) ? len_k2[b] : len_k1[b];
    const int m  = min(lp, lt);

    float local = 0.0f;
    if (m > 0) {
        const int nch = (m + chunk - 1) / chunk;
        for (int t = threadIdx.x; t < m; t += 256) {
            float M = NEG_INF_F, S = 0.0f;
            for (int sc = 0; sc < nch; ++sc) {
                const float2 p = partial[((size_t)(pb << 11) + t) * NS + sc];
                const float nM = fmaxf(M, p.x);
                S = S * __expf(M - nM) + p.y * __expf(p.x - nM);
                M = nM;
            }
            local += (__logf(S) + M) - diag[(pb << 11) + t];
        }
    }

    __shared__ float ws4[4];
    #pragma unroll
    for (int msk = 1; msk < 64; msk <<= 1)
        local += __shfl_xor(local, msk, 64);
    if ((threadIdx.x & 63) == 0) ws4[threadIdx.x >> 6] = local;
    __syncthreads();
    if (threadIdx.x == 0) {
        const float tot = ws4[0] + ws4[1] + ws4[2] + ws4[3];
        per_sample[pb] = (m > 0) ? (tot / (float)m) : 0.0f;
    }
}

__global__ void finalize_kernel(
    const int* __restrict__ len_q1, const int* __restrict__ len_k2,
    const int* __restrict__ len_q2, const int* __restrict__ len_k1,
    const float* __restrict__ per_sample, float* __restrict__ out)
{
    if (threadIdx.x != 0 || blockIdx.x != 0) return;
    float losses[2];
    #pragma unroll
    for (int p = 0; p < 2; ++p) {
        float tot = 0.0f, nv = 0.0f;
        for (int b = 0; b < B_DIM; ++b) {
            const int lp = (p == 0) ? len_q1[b] : len_q2[b];
            const int lt = (p == 0) ? len_k2[b] : len_k1[b];
            const int mm = min(lp, lt);
            if (mm > 0) { tot += per_sample[p * B_DIM + b]; nv += 1.0f; }
        }
        losses[p] = (nv > 0.0f) ? (tot / nv) : 0.0f;
    }
    out[0] = 0.5f * (losses[0] + losses[1]);
}

extern "C" void kernel_launch(void* const* d_in, const int* in_sizes, int n_in,
                              void* d_out, int out_size, void* d_ws, size_t ws_size,
                              hipStream_t stream) {
    const float* q1 = (const float*)d_in[0];
    const float* k2 = (const float*)d_in[1];
    const float* q2 = (const float*)d_in[2];
    const float* k1 = (const float*)d_in[3];
    const int* lq1 = (const int*)d_in[6];
    const int* lk2 = (const int*)d_in[7];
    const int* lq2 = (const int*)d_in[8];
    const int* lk1 = (const int*)d_in[9];
    float* out = (float*)d_out;

    const size_t rows = (size_t)2 * B_DIM * T_DIM;   // 65536
    int NS = 16;                                     // chunk=128 -> ~1370 active blocks
    while (NS > 1) {
        const size_t need = rows * NS * sizeof(float2) + rows * sizeof(float) + 256;
        if (need <= ws_size) break;
        NS >>= 1;
    }
    const int chunk = T_DIM / NS;

    float2* partial    = (float2*)d_ws;
    float*  diag       = (float*)((char*)d_ws + rows * NS * sizeof(float2));
    float*  per_sample = diag + rows;

    dim3 gridA(T_DIM / BM, B_DIM, 2 * NS);
    partial_lse_direct_kernel<<<gridA, 256, 0, stream>>>(
        q1, k2, q2, k1, lq1, lk2, lq2, lk1, partial, diag, chunk, NS);

    combine_kernel<<<32, 256, 0, stream>>>(
        lq1, lk2, lq2, lk1, partial, diag, per_sample, chunk, NS);

    finalize_kernel<<<1, 64, 0, stream>>>(lq1, lk2, lq2, lk1, per_sample, out);
}

// Round 7
// 77.689 us; speedup vs baseline: 3.6436x; 3.6436x over previous
//
#include <hip/hip_runtime.h>
#include <hip/hip_bf16.h>
#include <cmath>

#define T_DIM 2048
#define B_DIM 16
#define D_DIM 256
#define BD (B_DIM * D_DIM)
#define BM 256            // t-rows per block (8 waves x 32 rows)
#define BN 64             // s-rows per stage
#define NS 4              // s-chunks (chunk = 512)
#define CHUNK (T_DIM / NS)
#define NEG_INF_F (-1e30f)

typedef __attribute__((ext_vector_type(8))) short bf16x8;
typedef __attribute__((ext_vector_type(8))) unsigned short ushort8;
typedef __attribute__((ext_vector_type(4))) float f32x4;

static __device__ __forceinline__ ushort f2bf(float f) {
    union { float f; unsigned int u; } x; x.f = f;
    unsigned int r = (x.u + 0x7FFFu + ((x.u >> 16) & 1u)) >> 16;  // RNE
    return (ushort)r;
}

static __device__ __forceinline__ void gload_lds16(const ushort* g, ushort* l) {
    __builtin_amdgcn_global_load_lds(
        (const __attribute__((address_space(1))) unsigned int*)g,
        (__attribute__((address_space(3))) unsigned int*)l,
        16, 0, 0);
}

// ---------------- Pass 0: f32 -> bf16, pre-swizzled; preds x10 ----------------
__global__ __launch_bounds__(256) void convert_kernel(
    const float* __restrict__ q1, const float* __restrict__ k2,
    const float* __restrict__ q2, const float* __restrict__ k1,
    const int* __restrict__ lq1, const int* __restrict__ lk2,
    const int* __restrict__ lq2, const int* __restrict__ lk1,
    ushort* __restrict__ wsbf)
{
    const int idx    = blockIdx.x * 256 + threadIdx.x;
    const int tensor = idx >> 20;
    const int rem    = idx & 1048575;
    const int t      = rem >> 9;
    const int r2     = rem & 511;
    const int b      = r2 >> 5;
    const int d8     = (r2 & 31) * 8;
    const int m = (tensor < 2) ? min(lq1[b], lk2[b]) : min(lq2[b], lk1[b]);
    if (t >= m) return;

    const float* src = (tensor == 0) ? q1 : (tensor == 1) ? k2 : (tensor == 2) ? q2 : k1;
    const float scale = (tensor == 0 || tensor == 2) ? 10.0f : 1.0f;
    const size_t off = (size_t)t * BD + (size_t)b * D_DIM + d8;
    const float4 v0 = *reinterpret_cast<const float4*>(&src[off]);
    const float4 v1 = *reinterpret_cast<const float4*>(&src[off + 4]);
    ushort8 h;
    h[0] = f2bf(v0.x * scale); h[1] = f2bf(v0.y * scale);
    h[2] = f2bf(v0.z * scale); h[3] = f2bf(v0.w * scale);
    h[4] = f2bf(v1.x * scale); h[5] = f2bf(v1.y * scale);
    h[6] = f2bf(v1.z * scale); h[7] = f2bf(v1.w * scale);
    const size_t TBD = (size_t)T_DIM * BD;
    ushort* dst = &wsbf[(size_t)tensor * TBD + (size_t)t * BD + (size_t)b * D_DIM
                        + (d8 ^ ((t & 15) << 3))];
    *reinterpret_cast<ushort8*>(dst) = h;
}

// ---------------- Phase A: 256-row x 512-col tiles, 8 waves ----------------
__global__ __launch_bounds__(512) void partial_lse_bf_kernel(
    const ushort* __restrict__ wsbf,
    const int* __restrict__ len_q1, const int* __restrict__ len_k2,
    const int* __restrict__ len_q2, const int* __restrict__ len_k1,
    float2* __restrict__ partial, float* __restrict__ diag)
{
    const int pair = blockIdx.z / NS;
    const int sc   = blockIdx.z % NS;
    const int b    = blockIdx.y;
    const int t0   = blockIdx.x * BM;

    const int lp = (pair == 0) ? len_q1[b] : len_q2[b];
    const int lt = (pair == 0) ? len_k2[b] : len_k1[b];
    const int m  = min(lp, lt);
    const int s_start = sc * CHUNK;
    if (t0 >= m || s_start >= m) return;
    const int s_hi = min(m, s_start + CHUNK);
    const int pb = pair * B_DIM + b;

    const size_t TBD = (size_t)T_DIM * BD;
    const ushort* pred = wsbf + (size_t)(pair ? 2 : 0) * TBD;
    const ushort* targ = wsbf + (size_t)(pair ? 3 : 1) * TBD;

    __shared__ ushort tl[2][BN * 256];   // 2 x 32KB double buffer

    const int tid = threadIdx.x;
    const int w   = tid >> 6;     // wave 0..7
    const int l   = tid & 63;
    const int c   = l & 15;
    const int g   = l >> 4;

    // issue stage 0: wave w stages rows [8w, 8w+8) of the tile (4 x 16B/lane)
    #pragma unroll
    for (int q = 0; q < 4; ++q) {
        const int r = 8 * w + 2 * q + (l >> 5);
        const ushort* gp = &targ[(size_t)(s_start + r) * BD + (size_t)b * D_DIM + (l & 31) * 8];
        gload_lds16(gp, &tl[0][(4 * w + q) * 512]);
    }

    // ---- preload pred rows [t0+32w, +32) as A-fragments (pre-scaled, pre-swizzled)
    bf16x8 afrag[2][8];
    #pragma unroll
    for (int i = 0; i < 2; ++i) {
        const ushort* base = &pred[(size_t)(t0 + 32 * w + 16 * i + c) * BD + (size_t)b * D_DIM];
        #pragma unroll
        for (int kk = 0; kk < 8; ++kk) {
            const int d = g * 8 + kk * 32;
            afrag[i][kk] = *reinterpret_cast<const bf16x8*>(&base[d ^ (c << 3)]);
        }
    }

    float tmax[2][4], tsum[2][4], dg[2][4];
    #pragma unroll
    for (int i = 0; i < 2; ++i)
        #pragma unroll
        for (int rr = 0; rr < 4; ++rr) {
            tmax[i][rr] = NEG_INF_F; tsum[i][rr] = 0.0f; dg[i][rr] = NEG_INF_F;
        }

    __syncthreads();   // stage 0 landed
    int cur = 0;

    for (int s0 = s_start; s0 < s_hi; s0 += BN) {
        if (s0 + BN < s_hi) {
            const int nxt = cur ^ 1;
            #pragma unroll
            for (int q = 0; q < 4; ++q) {
                const int r = 8 * w + 2 * q + (l >> 5);
                const ushort* gp = &targ[(size_t)(s0 + BN + r) * BD + (size_t)b * D_DIM + (l & 31) * 8];
                gload_lds16(gp, &tl[nxt][(4 * w + q) * 512]);
            }
        }

        f32x4 acc[2][4];
        #pragma unroll
        for (int i = 0; i < 2; ++i)
            #pragma unroll
            for (int j = 0; j < 4; ++j)
                acc[i][j] = (f32x4){0.f, 0.f, 0.f, 0.f};

        const ushort* buf = tl[cur];
        #pragma unroll
        for (int kk = 0; kk < 8; ++kk) {
            bf16x8 bfrag[4];
            #pragma unroll
            for (int j = 0; j < 4; ++j) {
                const int r = 16 * j + c;
                const int d = g * 8 + kk * 32;
                bfrag[j] = *reinterpret_cast<const bf16x8*>(&buf[(r << 8) + (d ^ (c << 3))]);
            }
            #pragma unroll
            for (int i = 0; i < 2; ++i)
                #pragma unroll
                for (int j = 0; j < 4; ++j)
                    acc[i][j] = __builtin_amdgcn_mfma_f32_16x16x32_bf16(
                        afrag[i][kk], bfrag[j], acc[i][j], 0, 0, 0);
        }

        #pragma unroll
        for (int i = 0; i < 2; ++i) {
            #pragma unroll
            for (int rr = 0; rr < 4; ++rr) {
                const int trow = t0 + 32 * w + 16 * i + 4 * g + rr;
                float lg[4];
                float cmax = NEG_INF_F;
                #pragma unroll
                for (int j = 0; j < 4; ++j) {
                    const int s = s0 + 16 * j + c;
                    float v = acc[i][j][rr];
                    v = (s < m) ? v : NEG_INF_F;
                    if (s == trow) dg[i][rr] = v;
                    lg[j] = v;
                    cmax = fmaxf(cmax, v);
                }
                const float nmax = fmaxf(tmax[i][rr], cmax);
                const float add = __expf(lg[0] - nmax) + __expf(lg[1] - nmax)
                                + __expf(lg[2] - nmax) + __expf(lg[3] - nmax);
                tsum[i][rr] = tsum[i][rr] * __expf(tmax[i][rr] - nmax) + add;
                tmax[i][rr] = nmax;
            }
        }

        __syncthreads();
        cur ^= 1;
    }

    // ---- 16-lane LSE merge + writes
    // each 256-aligned t-tile lies wholly inside one 512 chunk -> this sc owns
    // the diagonal iff t-range within s-range:
    const bool own_diag = (t0 >= s_start) && (t0 + BM <= s_start + CHUNK);
    #pragma unroll
    for (int i = 0; i < 2; ++i) {
        #pragma unroll
        for (int rr = 0; rr < 4; ++rr) {
            float M = tmax[i][rr], S = tsum[i][rr];
            #pragma unroll
            for (int msk = 1; msk < 16; msk <<= 1) {
                const float Mo = __shfl_xor(M, msk, 64);
                const float So = __shfl_xor(S, msk, 64);
                const float nM = fmaxf(M, Mo);
                S = S * __expf(M - nM) + So * __expf(Mo - nM);
                M = nM;
            }
            float d = dg[i][rr];
            #pragma unroll
            for (int msk = 1; msk < 16; msk <<= 1)
                d = fmaxf(d, __shfl_xor(d, msk, 64));
            if (c == 0) {
                const int trow = t0 + 32 * w + 16 * i + 4 * g + rr;
                partial[((size_t)(pb << 11) + trow) * NS + sc] = make_float2(M, S);
                if (own_diag) diag[(pb << 11) + trow] = d;
            }
        }
    }
}

// ---------------- Phase A fallback (f32 inputs, in-kernel convert) ----------------
__global__ __launch_bounds__(256) void partial_lse_f32_kernel(
    const float* __restrict__ q1, const float* __restrict__ k2,
    const float* __restrict__ q2, const float* __restrict__ k1,
    const int* __restrict__ len_q1, const int* __restrict__ len_k2,
    const int* __restrict__ len_q2, const int* __restrict__ len_k1,
    float2* __restrict__ partial, float* __restrict__ diag,
    int chunk, int ns)
{
    const int pair = blockIdx.z / ns;
    const int sc   = blockIdx.z % ns;
    const int b    = blockIdx.y;
    const int t0   = blockIdx.x * 128;

    const float* pred = (pair == 0) ? q1 : q2;
    const float* targ = (pair == 0) ? k2 : k1;
    const int lp = (pair == 0) ? len_q1[b] : len_q2[b];
    const int lt = (pair == 0) ? len_k2[b] : len_k1[b];
    const int m  = min(lp, lt);
    const int s_start = sc * chunk;
    if (t0 >= m || s_start >= m) return;
    const int s_hi = min(m, s_start + chunk);
    const int pb = pair * B_DIM + b;

    __shared__ ushort tlf[BN * 256];

    const int tid = threadIdx.x;
    const int w   = tid >> 6;
    const int l   = tid & 63;
    const int c   = l & 15;
    const int g   = l >> 4;

    bf16x8 afrag[2][8];
    #pragma unroll
    for (int i = 0; i < 2; ++i) {
        const float* base = &pred[(size_t)(t0 + 32 * w + 16 * i + c) * BD + (size_t)b * D_DIM];
        #pragma unroll
        for (int kk = 0; kk < 8; ++kk) {
            const int d = g * 8 + kk * 32;
            const float4 v0 = *reinterpret_cast<const float4*>(base + d);
            const float4 v1 = *reinterpret_cast<const float4*>(base + d + 4);
            bf16x8 av;
            av[0] = (short)f2bf(v0.x * 10.f); av[1] = (short)f2bf(v0.y * 10.f);
            av[2] = (short)f2bf(v0.z * 10.f); av[3] = (short)f2bf(v0.w * 10.f);
            av[4] = (short)f2bf(v1.x * 10.f); av[5] = (short)f2bf(v1.y * 10.f);
            av[6] = (short)f2bf(v1.z * 10.f); av[7] = (short)f2bf(v1.w * 10.f);
            afrag[i][kk] = av;
        }
    }

    float tmax[2][4], tsum[2][4], dg[2][4];
    #pragma unroll
    for (int i = 0; i < 2; ++i)
        #pragma unroll
        for (int rr = 0; rr < 4; ++rr) {
            tmax[i][rr] = NEG_INF_F; tsum[i][rr] = 0.0f; dg[i][rr] = NEG_INF_F;
        }

    for (int s0 = s_start; s0 < s_hi; s0 += BN) {
        __syncthreads();
        #pragma unroll
        for (int v = 0; v < 16; ++v) {
            const int f  = v * 256 + tid;
            const int r  = f >> 6;
            const int d0 = (f & 63) * 4;
            const float4 vv = *reinterpret_cast<const float4*>(
                &targ[(size_t)(s0 + r) * BD + (size_t)b * D_DIM + d0]);
            ushort4 h;
            h.x = f2bf(vv.x); h.y = f2bf(vv.y); h.z = f2bf(vv.z); h.w = f2bf(vv.w);
            *reinterpret_cast<ushort4*>(&tlf[(r << 8) + (d0 ^ ((r & 15) << 3))]) = h;
        }
        __syncthreads();

        f32x4 acc[2][4];
        #pragma unroll
        for (int i = 0; i < 2; ++i)
            #pragma unroll
            for (int j = 0; j < 4; ++j)
                acc[i][j] = (f32x4){0.f, 0.f, 0.f, 0.f};

        #pragma unroll
        for (int kk = 0; kk < 8; ++kk) {
            bf16x8 bfrag[4];
            #pragma unroll
            for (int j = 0; j < 4; ++j) {
                const int r = 16 * j + c;
                const int d = g * 8 + kk * 32;
                bfrag[j] = *reinterpret_cast<const bf16x8*>(&tlf[(r << 8) + (d ^ (c << 3))]);
            }
            #pragma unroll
            for (int i = 0; i < 2; ++i)
                #pragma unroll
                for (int j = 0; j < 4; ++j)
                    acc[i][j] = __builtin_amdgcn_mfma_f32_16x16x32_bf16(
                        afrag[i][kk], bfrag[j], acc[i][j], 0, 0, 0);
        }

        #pragma unroll
        for (int i = 0; i < 2; ++i) {
            #pragma unroll
            for (int rr = 0; rr < 4; ++rr) {
                const int trow = t0 + 32 * w + 16 * i + 4 * g + rr;
                float lg[4];
                float cmax = NEG_INF_F;
                #pragma unroll
                for (int j = 0; j < 4; ++j) {
                    const int s = s0 + 16 * j + c;
                    float v = acc[i][j][rr];
                    v = (s < m) ? v : NEG_INF_F;
                    if (s == trow) dg[i][rr] = v;
                    lg[j] = v;
                    cmax = fmaxf(cmax, v);
                }
                const float nmax = fmaxf(tmax[i][rr], cmax);
                const float add = __expf(lg[0] - nmax) + __expf(lg[1] - nmax)
                                + __expf(lg[2] - nmax) + __expf(lg[3] - nmax);
                tsum[i][rr] = tsum[i][rr] * __expf(tmax[i][rr] - nmax) + add;
                tmax[i][rr] = nmax;
            }
        }
    }

    const bool own_diag = (t0 >= s_start) && (t0 + 128 <= s_start + chunk);
    #pragma unroll
    for (int i = 0; i < 2; ++i) {
        #pragma unroll
        for (int rr = 0; rr < 4; ++rr) {
            float M = tmax[i][rr], S = tsum[i][rr];
            #pragma unroll
            for (int msk = 1; msk < 16; msk <<= 1) {
                const float Mo = __shfl_xor(M, msk, 64);
                const float So = __shfl_xor(S, msk, 64);
                const float nM = fmaxf(M, Mo);
                S = S * __expf(M - nM) + So * __expf(Mo - nM);
                M = nM;
            }
            float d = dg[i][rr];
            #pragma unroll
            for (int msk = 1; msk < 16; msk <<= 1)
                d = fmaxf(d, __shfl_xor(d, msk, 64));
            if (c == 0) {
                const int trow = t0 + 32 * w + 16 * i + 4 * g + rr;
                partial[((size_t)(pb << 11) + trow) * ns + sc] = make_float2(M, S);
                if (own_diag) diag[(pb << 11) + trow] = d;
            }
        }
    }
}

// ---------------- Phase B ----------------
__global__ __launch_bounds__(256) void combine_kernel(
    const int* __restrict__ len_q1, const int* __restrict__ len_k2,
    const int* __restrict__ len_q2, const int* __restrict__ len_k1,
    const float2* __restrict__ partial, const float* __restrict__ diag,
    float* __restrict__ per_sample, int chunk, int ns)
{
    const int pb   = blockIdx.x;
    const int pair = pb >> 4;
    const int b    = pb & 15;
    const int lp = (pair == 0) ? len_q1[b] : len_q2[b];
    const int lt = (pair == 0) ? len_k2[b] : len_k1[b];
    const int m  = min(lp, lt);

    float local = 0.0f;
    if (m > 0) {
        const int nch = (m + chunk - 1) / chunk;
        for (int t = threadIdx.x; t < m; t += 256) {
            float M = NEG_INF_F, S = 0.0f;
            for (int sc = 0; sc < nch; ++sc) {
                const float2 p = partial[((size_t)(pb << 11) + t) * ns + sc];
                const float nM = fmaxf(M, p.x);
                S = S * __expf(M - nM) + p.y * __expf(p.x - nM);
                M = nM;
            }
            local += (__logf(S) + M) - diag[(pb << 11) + t];
        }
    }

    __shared__ float ws4[4];
    #pragma unroll
    for (int msk = 1; msk < 64; msk <<= 1)
        local += __shfl_xor(local, msk, 64);
    if ((threadIdx.x & 63) == 0) ws4[threadIdx.x >> 6] = local;
    __syncthreads();
    if (threadIdx.x == 0) {
        const float tot = ws4[0] + ws4[1] + ws4[2] + ws4[3];
        per_sample[pb] = (m > 0) ? (tot / (float)m) : 0.0f;
    }
}

__global__ void finalize_kernel(
    const int* __restrict__ len_q1, const int* __restrict__ len_k2,
    const int* __restrict__ len_q2, const int* __restrict__ len_k1,
    const float* __restrict__ per_sample, float* __restrict__ out)
{
    if (threadIdx.x != 0 || blockIdx.x != 0) return;
    float losses[2];
    #pragma unroll
    for (int p = 0; p < 2; ++p) {
        float tot = 0.0f, nv = 0.0f;
        for (int b = 0; b < B_DIM; ++b) {
            const int lp = (p == 0) ? len_q1[b] : len_q2[b];
            const int lt = (p == 0) ? len_k2[b] : len_k1[b];
            const int mm = min(lp, lt);
            if (mm > 0) { tot += per_sample[p * B_DIM + b]; nv += 1.0f; }
        }
        losses[p] = (nv > 0.0f) ? (tot / nv) : 0.0f;
    }
    out[0] = 0.5f * (losses[0] + losses[1]);
}

extern "C" void kernel_launch(void* const* d_in, const int* in_sizes, int n_in,
                              void* d_out, int out_size, void* d_ws, size_t ws_size,
                              hipStream_t stream) {
    const float* q1 = (const float*)d_in[0];
    const float* k2 = (const float*)d_in[1];
    const float* q2 = (const float*)d_in[2];
    const float* k1 = (const float*)d_in[3];
    const int* lq1 = (const int*)d_in[6];
    const int* lk2 = (const int*)d_in[7];
    const int* lq2 = (const int*)d_in[8];
    const int* lk1 = (const int*)d_in[9];
    float* out = (float*)d_out;

    const size_t TBD  = (size_t)T_DIM * BD;
    const size_t rows = (size_t)2 * B_DIM * T_DIM;
    const size_t bfbytes = 4 * TBD * sizeof(ushort);   // 67.1 MB
    const size_t need_pre = bfbytes + rows * NS * sizeof(float2) + rows * sizeof(float) + 256;

    if (ws_size >= need_pre) {
        ushort* wsbf       = (ushort*)d_ws;
        float2* partial    = (float2*)((char*)d_ws + bfbytes);
        float*  diag       = (float*)((char*)partial + rows * NS * sizeof(float2));
        float*  per_sample = diag + rows;

        convert_kernel<<<16384, 256, 0, stream>>>(q1, k2, q2, k1, lq1, lk2, lq2, lk1, wsbf);

        dim3 gridA(T_DIM / BM, B_DIM, 2 * NS);   // 8 x 16 x 8 = 1024
        partial_lse_bf_kernel<<<gridA, 512, 0, stream>>>(
            wsbf, lq1, lk2, lq2, lk1, partial, diag);

        combine_kernel<<<32, 256, 0, stream>>>(
            lq1, lk2, lq2, lk1, partial, diag, per_sample, CHUNK, NS);
        finalize_kernel<<<1, 64, 0, stream>>>(lq1, lk2, lq2, lk1, per_sample, out);
    } else {
        int ns = 8;
        while (ns > 1) {
            const size_t need = rows * ns * sizeof(float2) + rows * sizeof(float) + 256;
            if (need <= ws_size) break;
            ns >>= 1;
        }
        const int chunk = T_DIM / ns;
        float2* partial    = (float2*)d_ws;
        float*  diag       = (float*)((char*)d_ws + rows * ns * sizeof(float2));
        float*  per_sample = diag + rows;

        dim3 gridA(T_DIM / 128, B_DIM, 2 * ns);
        partial_lse_f32_kernel<<<gridA, 256, 0, stream>>>(
            q1, k2, q2, k1, lq1, lk2, lq2, lk1, partial, diag, chunk, ns);

        combine_kernel<<<32, 256, 0, stream>>>(
            lq1, lk2, lq2, lk1, partial, diag, per_sample, chunk, ns);
        finalize_kernel<<<1, 64, 0, stream>>>(lq1, lk2, lq2, lk1, per_sample, out);
    }
}